// Round 16
// baseline (81.691 us; speedup 1.0000x reference)
//
#include <hip/hip_runtime.h>
#include <hip/hip_bf16.h>

typedef __attribute__((ext_vector_type(8))) short short8;
typedef __attribute__((ext_vector_type(4))) float floatx4;

#define B_ROWS 8192
#define DIM 128
#define NPAIR 4095
// rows scaled by sqrt(log2(e)) so S_mfma = S * log2(e) and exp(S) = exp2(S_mfma)
#define RSCALE 1.2011224087864498f

#define GLOAD_LDS16(gp, lp)                                                     \
    __builtin_amdgcn_global_load_lds(                                           \
        (const __attribute__((address_space(1))) void*)(gp),                    \
        (__attribute__((address_space(3))) void*)(lp), 16, 0, 0)

// ------------- prep: normalize rows -> bf16 (scaled), exact fp32 pair dots -------------
// 1024 blocks x 256 thr; wave W: rows 2W (lanes 0-31), 2W+1 (lanes 32-63), float4/lane.
// Also zeroes out[0] and the 64 per-panel counters (block 0).
__global__ void kprep(const float* __restrict__ X, __hip_bfloat16* __restrict__ XN,
                      float* __restrict__ pairT, float* __restrict__ out,
                      int* __restrict__ cnt) {
    const int wid = threadIdx.x >> 6;
    const int lane = threadIdx.x & 63;
    const int j = lane & 31;
    const int W = blockIdx.x * 4 + wid;  // wave index == pair index
    const int row = 2 * W + (lane >> 5);

    const float4 v = *reinterpret_cast<const float4*>(X + row * DIM + j * 4);
    float ss = v.x * v.x + v.y * v.y + v.z * v.z + v.w * v.w;
    #pragma unroll
    for (int m = 1; m < 32; m <<= 1) ss += __shfl_xor(ss, m, 64);  // within half
    const float rn = ss > 0.f ? rsqrtf(ss) : 0.f;

    // exact pair similarity via cross-half shuffle
    float4 pv;
    pv.x = __shfl_xor(v.x, 32, 64);
    pv.y = __shfl_xor(v.y, 32, 64);
    pv.z = __shfl_xor(v.z, 32, 64);
    pv.w = __shfl_xor(v.w, 32, 64);
    float pd = v.x * pv.x + v.y * pv.y + v.z * pv.z + v.w * pv.w;
    #pragma unroll
    for (int m = 1; m < 32; m <<= 1) pd += __shfl_xor(pd, m, 64);
    const float rno = __shfl_xor(rn, 32, 64);
    if (lane == 0 && W < NPAIR) pairT[W] = pd * rn * rno;

    // bf16 write (scaled)
    const float sc = rn * RSCALE;
    __hip_bfloat162 h0 = __float22bfloat162_rn(make_float2(v.x * sc, v.y * sc));
    __hip_bfloat162 h1 = __float22bfloat162_rn(make_float2(v.z * sc, v.w * sc));
    struct B4 { __hip_bfloat162 a, b; };
    *reinterpret_cast<B4*>(XN + row * DIM + j * 4) = B4{h0, h1};

    if (blockIdx.x == 0) {
        if (threadIdx.x == 0) out[0] = 0.f;
        if (threadIdx.x < 64) cnt[threadIdx.x] = 0;
    }
}

// ---- stage one 64x128 bf16 half-slab to LDS (linear dest, pre-swizzled source) ----
__device__ __forceinline__ void stage_half(const __hip_bfloat16* __restrict__ gsrc,
                                           __hip_bfloat16* lbuf, int tid) {
    const int wid = tid >> 6;
    const int lane = tid & 63;
    #pragma unroll
    for (int it = 0; it < 4; ++it) {
        const int woff = it * 2048 + wid * 512;  // wave-uniform elem offset
        const int e = woff + lane * 8;
        const int src = (e & ~127) | ((e & 127) ^ (((e >> 7) & 7) << 3));
        GLOAD_LDS16(gsrc + src, lbuf + woff);
    }
}

// ------------- main: r8 GEMM core + fused per-panel final reduction -------------
// 512 blocks 1-D, XCD-swizzled decode: rb = id & 63 (row panel), g = id >> 6
// (col group) -> all 8 blocks of a panel share id%8 == rb%8 (same XCD).
// 4 waves 2x2; 3-buffer counted-vmcnt half-slab pipeline (16 phases).
// After storing P[row][16] slots, blocks bump cnt[rb]; the 8th block reduces
// the panel's 128 rows (logZ) + 64 pair terms and atomically adds to out.
__global__ void __launch_bounds__(256, 2) kgemm(const __hip_bfloat16* __restrict__ XN,
                                                float* __restrict__ P,
                                                const float* __restrict__ pairT,
                                                float* __restrict__ out,
                                                int* __restrict__ cnt) {
    __shared__ __hip_bfloat16 Bs[3][64 * DIM];

    const int tid = threadIdx.x;
    const int wid = tid >> 6;
    const int lane = tid & 63;
    const int lr = lane & 15;
    const int lk = lane >> 4;
    const int wr = wid >> 1;
    const int wc = wid & 1;
    const int id = blockIdx.x;
    const int rb = id & 63;    // panel: id % 8 == rb % 8 -> panel-mates same XCD
    const int g = id >> 6;

    // A: 64 rows in registers: a[kk][m], rows rb*128 + wr*64 + m*16 + lr
    short8 a[4][4];
    const __hip_bfloat16* Abase = XN + (rb * 128 + wr * 64 + lr) * DIM + lk * 8;
    #pragma unroll
    for (int m = 0; m < 4; ++m)
        #pragma unroll
        for (int kk = 0; kk < 4; ++kk)
            a[kk][m] = *reinterpret_cast<const short8*>(Abase + m * 16 * DIM + kk * 32);

    float rp[4][4];
    #pragma unroll
    for (int m = 0; m < 4; ++m)
        #pragma unroll
        for (int r = 0; r < 4; ++r) rp[m][r] = 0.f;

    const floatx4 zero4 = {0.f, 0.f, 0.f, 0.f};

    // prologue: stage slabs 0,1 (slab s = tile g*8 + (s>>1), half s&1)
    stage_half(XN + (size_t)(g * 8) * 128 * DIM, Bs[0], tid);
    stage_half(XN + ((size_t)(g * 8) * 128 + 64) * DIM, Bs[1], tid);

    for (int t = 0; t < 16; ++t) {
        if (t < 15)
            asm volatile("s_waitcnt vmcnt(4)" ::: "memory");
        else
            asm volatile("s_waitcnt vmcnt(0)" ::: "memory");
        __builtin_amdgcn_s_barrier();  // raw barrier: no drain

        if (t + 2 < 16)
            stage_half(XN + ((size_t)(g * 8 + ((t + 2) >> 1)) * 128 + ((t + 2) & 1) * 64) * DIM,
                       Bs[(t + 2) % 3], tid);

        const __hip_bfloat16* Bt = Bs[t % 3];
        const bool dzero = (g * 8 + (t >> 1) == rb) && ((t & 1) == wr);

        __builtin_amdgcn_s_setprio(1);
        short8 b[4][2];
        #pragma unroll
        for (int n = 0; n < 2; ++n) {
            const int row = wc * 32 + n * 16 + lr;
            #pragma unroll
            for (int kk = 0; kk < 4; ++kk) {
                const int col = (kk * 32 + lk * 8) ^ ((row & 7) << 3);
                b[kk][n] = *reinterpret_cast<const short8*>(&Bt[row * DIM + col]);
            }
        }

        floatx4 acc[4][2];
        #pragma unroll
        for (int m = 0; m < 4; ++m)
            #pragma unroll
            for (int n = 0; n < 2; ++n)
                acc[m][n] = __builtin_amdgcn_mfma_f32_16x16x32_bf16(a[0][m], b[0][n], zero4, 0, 0, 0);
        #pragma unroll
        for (int kk = 1; kk < 4; ++kk)
            #pragma unroll
            for (int m = 0; m < 4; ++m)
                #pragma unroll
                for (int n = 0; n < 2; ++n)
                    acc[m][n] = __builtin_amdgcn_mfma_f32_16x16x32_bf16(a[kk][m], b[kk][n], acc[m][n], 0, 0, 0);
        __builtin_amdgcn_s_setprio(0);

        if (dzero) {
            #pragma unroll
            for (int m = 0; m < 4; ++m)
                #pragma unroll
                for (int n = 0; n < 2; ++n)
                    #pragma unroll
                    for (int r = 0; r < 4; ++r) {
                        float e = __builtin_amdgcn_exp2f(acc[m][n][r]);
                        if (m * 16 + lk * 4 + r == wc * 32 + n * 16 + lr) e = 0.f;
                        rp[m][r] += e;
                    }
        } else {
            #pragma unroll
            for (int m = 0; m < 4; ++m)
                #pragma unroll
                for (int n = 0; n < 2; ++n)
                    #pragma unroll
                    for (int r = 0; r < 4; ++r)
                        rp[m][r] += __builtin_amdgcn_exp2f(acc[m][n][r]);
        }
    }

    // ---- row sums: reduce over lr, store P[row][slot] (transposed: 64B/row) ----
    #pragma unroll
    for (int m = 0; m < 4; ++m)
        #pragma unroll
        for (int r = 0; r < 4; ++r) {
            float v = rp[m][r];
            v += __shfl_xor(v, 1, 64);
            v += __shfl_xor(v, 2, 64);
            v += __shfl_xor(v, 4, 64);
            v += __shfl_xor(v, 8, 64);
            if (lr == 0) {
                const int row = rb * 128 + wr * 64 + m * 16 + lk * 4 + r;
                P[row * 16 + (g * 2 + wc)] = v;
            }
        }

    // ---- fused finalization: 8th block of this panel reduces it ----
    __threadfence();   // release P stores (device scope; panel-mates same XCD)
    __syncthreads();   // all waves' stores precede the counter bump
    if (wid == 0) {    // wave 0 only
        int done = 0;
        if (lane == 0) done = (atomicAdd(&cnt[rb], 1) == 7) ? 1 : 0;
        done = __shfl(done, 0, 64);
        if (done) {
            __threadfence();  // acquire other blocks' P stores
            float s = 0.f;
            #pragma unroll
            for (int rr = 0; rr < 2; ++rr) {
                const int row = rb * 128 + lane * 2 + rr;
                if (row < B_ROWS - 2) {
                    const float4* p4 = reinterpret_cast<const float4*>(P + row * 16);
                    float z = 0.f;
                    #pragma unroll
                    for (int i = 0; i < 4; ++i) {
                        const float4 vv = p4[i];
                        z += vv.x + vv.y + vv.z + vv.w;
                    }
                    s += logf(z);
                }
            }
            const int p = rb * 64 + lane;
            if (p < NPAIR) s -= 2.f * pairT[p];
            #pragma unroll
            for (int m = 1; m < 64; m <<= 1) s += __shfl_xor(s, m, 64);
            if (lane == 0) atomicAdd(out, s / (float)B_ROWS);
        }
    }
}

extern "C" void kernel_launch(void* const* d_in, const int* in_sizes, int n_in,
                              void* d_out, int out_size, void* d_ws, size_t ws_size,
                              hipStream_t stream) {
    (void)in_sizes; (void)n_in; (void)out_size; (void)ws_size;
    const float* X = (const float*)d_in[0];
    float* out = (float*)d_out;
    char* ws = (char*)d_ws;

    int* cnt = (int*)ws;                                     // 256 B (64 counters)
    float* pairT = (float*)(ws + 4096);                      // 16 KB
    __hip_bfloat16* XN = (__hip_bfloat16*)(ws + 32768);      // 2 MB
    float* P = (float*)(ws + 32768 + 2097152);               // 512 KB (8192 x 16 f32)

    kprep<<<1024, 256, 0, stream>>>(X, XN, pairT, out, cnt);
    kgemm<<<512, 256, 0, stream>>>(XN, P, pairT, out, cnt);
}

// Round 17
// 37.383 us; speedup vs baseline: 2.1853x; 2.1853x over previous
//
#include <hip/hip_runtime.h>
#include <hip/hip_bf16.h>

typedef __attribute__((ext_vector_type(8))) short short8;
typedef __attribute__((ext_vector_type(4))) float floatx4;

#define B_ROWS 8192
#define DIM 128
#define NPAIR 4095
// rows scaled by sqrt(log2(e)) so S_mfma = S * log2(e) and exp(S) = exp2(S_mfma)
#define RSCALE 1.2011224087864498f

#define GLOAD_LDS16(gp, lp)                                                     \
    __builtin_amdgcn_global_load_lds(                                           \
        (const __attribute__((address_space(1))) void*)(gp),                    \
        (__attribute__((address_space(3))) void*)(lp), 16, 0, 0)

// ---------------- zero Z (fallback path only) ----------------
__global__ void kzero(float* __restrict__ Z) {
    int i = blockIdx.x * 256 + threadIdx.x;
    if (i < B_ROWS) Z[i] = 0.f;
}

// ------------- prep: normalize rows -> bf16 (scaled), exact fp32 pair dots -------------
// 1024 blocks x 256 thr; wave W: rows 2W (lanes 0-31), 2W+1 (lanes 32-63), float4/lane.
__global__ void kprep(const float* __restrict__ X, __hip_bfloat16* __restrict__ XN,
                      float* __restrict__ pairT, float* __restrict__ out) {
    const int wid = threadIdx.x >> 6;
    const int lane = threadIdx.x & 63;
    const int j = lane & 31;
    const int W = blockIdx.x * 4 + wid;  // wave index == pair index
    const int row = 2 * W + (lane >> 5);

    const float4 v = *reinterpret_cast<const float4*>(X + row * DIM + j * 4);
    float ss = v.x * v.x + v.y * v.y + v.z * v.z + v.w * v.w;
    #pragma unroll
    for (int m = 1; m < 32; m <<= 1) ss += __shfl_xor(ss, m, 64);  // within half
    const float rn = ss > 0.f ? rsqrtf(ss) : 0.f;

    // exact pair similarity via cross-half shuffle
    float4 pv;
    pv.x = __shfl_xor(v.x, 32, 64);
    pv.y = __shfl_xor(v.y, 32, 64);
    pv.z = __shfl_xor(v.z, 32, 64);
    pv.w = __shfl_xor(v.w, 32, 64);
    float pd = v.x * pv.x + v.y * pv.y + v.z * pv.z + v.w * pv.w;
    #pragma unroll
    for (int m = 1; m < 32; m <<= 1) pd += __shfl_xor(pd, m, 64);
    const float rno = __shfl_xor(rn, 32, 64);
    if (lane == 0 && W < NPAIR) pairT[W] = pd * rn * rno;

    // bf16 write (scaled)
    const float sc = rn * RSCALE;
    __hip_bfloat162 h0 = __float22bfloat162_rn(make_float2(v.x * sc, v.y * sc));
    __hip_bfloat162 h1 = __float22bfloat162_rn(make_float2(v.z * sc, v.w * sc));
    struct B4 { __hip_bfloat162 a, b; };
    *reinterpret_cast<B4*>(XN + row * DIM + j * 4) = B4{h0, h1};

    if (W == 0 && lane == 0) out[0] = 0.f;
}

// ---- stage one 64x128 bf16 half-slab to LDS (linear dest, pre-swizzled source) ----
__device__ __forceinline__ void stage_half(const __hip_bfloat16* __restrict__ gsrc,
                                           __hip_bfloat16* lbuf, int tid) {
    const int wid = tid >> 6;
    const int lane = tid & 63;
    #pragma unroll
    for (int it = 0; it < 4; ++it) {
        const int woff = it * 2048 + wid * 512;  // wave-uniform elem offset
        const int e = woff + lane * 8;
        const int src = (e & ~127) | ((e & 127) ^ (((e >> 7) & 7) << 3));
        GLOAD_LDS16(gsrc + src, lbuf + woff);
    }
}

// ------------- main: r8 pipeline at 1024-block geometry, 3 waves/SIMD -------------
// grid (16, 64): y = row panel rb (128 rows), x = col group g (512 cols = 8 slabs).
// 4 waves 2x2 (wr row-half, wc col-half); 3-buffer counted-vmcnt half-slab pipeline,
// 8 phases/block. launch_bounds(256,3) caps VGPR at 170 -> 3 blocks/CU co-resident.
template <bool USEP>
__global__ void __launch_bounds__(256, 3) kgemm(const __hip_bfloat16* __restrict__ XN,
                                                float* __restrict__ ZP) {
    __shared__ __hip_bfloat16 Bs[3][64 * DIM];

    const int tid = threadIdx.x;
    const int wid = tid >> 6;
    const int lane = tid & 63;
    const int lr = lane & 15;
    const int lk = lane >> 4;
    const int wr = wid >> 1;
    const int wc = wid & 1;
    const int rb = blockIdx.y;
    const int g = blockIdx.x;

    // A: 64 rows in registers: a[kk][m], rows rb*128 + wr*64 + m*16 + lr
    short8 a[4][4];
    const __hip_bfloat16* Abase = XN + (rb * 128 + wr * 64 + lr) * DIM + lk * 8;
    #pragma unroll
    for (int m = 0; m < 4; ++m)
        #pragma unroll
        for (int kk = 0; kk < 4; ++kk)
            a[kk][m] = *reinterpret_cast<const short8*>(Abase + m * 16 * DIM + kk * 32);

    float rp[4][4];
    #pragma unroll
    for (int m = 0; m < 4; ++m)
        #pragma unroll
        for (int r = 0; r < 4; ++r) rp[m][r] = 0.f;

    const floatx4 zero4 = {0.f, 0.f, 0.f, 0.f};

    // prologue: stage slabs 0,1 (slab s covers cols g*512 + s*64)
    stage_half(XN + (size_t)(g * 512) * DIM, Bs[0], tid);
    stage_half(XN + (size_t)(g * 512 + 64) * DIM, Bs[1], tid);

    const int myblk = rb * 2 + wr;  // wave's 64-row block index

    for (int t = 0; t < 8; ++t) {
        // counted wait: slab t's 4 loads landed; slab t+1 stays in flight
        if (t < 7)
            asm volatile("s_waitcnt vmcnt(4)" ::: "memory");
        else
            asm volatile("s_waitcnt vmcnt(0)" ::: "memory");
        __builtin_amdgcn_s_barrier();  // raw barrier: no drain

        if (t + 2 < 8)
            stage_half(XN + (size_t)(g * 512 + (t + 2) * 64) * DIM, Bs[(t + 2) % 3], tid);

        const __hip_bfloat16* Bt = Bs[t % 3];
        const bool dzero = (g * 8 + t == myblk);  // slab aligns with wave's rows

        __builtin_amdgcn_s_setprio(1);
        short8 b[4][2];
        #pragma unroll
        for (int n = 0; n < 2; ++n) {
            const int row = wc * 32 + n * 16 + lr;
            #pragma unroll
            for (int kk = 0; kk < 4; ++kk) {
                const int col = (kk * 32 + lk * 8) ^ ((row & 7) << 3);
                b[kk][n] = *reinterpret_cast<const short8*>(&Bt[row * DIM + col]);
            }
        }

        floatx4 acc[4][2];
        #pragma unroll
        for (int m = 0; m < 4; ++m)
            #pragma unroll
            for (int n = 0; n < 2; ++n)
                acc[m][n] = __builtin_amdgcn_mfma_f32_16x16x32_bf16(a[0][m], b[0][n], zero4, 0, 0, 0);
        #pragma unroll
        for (int kk = 1; kk < 4; ++kk)
            #pragma unroll
            for (int m = 0; m < 4; ++m)
                #pragma unroll
                for (int n = 0; n < 2; ++n)
                    acc[m][n] = __builtin_amdgcn_mfma_f32_16x16x32_bf16(a[kk][m], b[kk][n], acc[m][n], 0, 0, 0);
        __builtin_amdgcn_s_setprio(0);

        if (dzero) {
            #pragma unroll
            for (int m = 0; m < 4; ++m)
                #pragma unroll
                for (int n = 0; n < 2; ++n)
                    #pragma unroll
                    for (int r = 0; r < 4; ++r) {
                        float e = __builtin_amdgcn_exp2f(acc[m][n][r]);
                        if (m * 16 + lk * 4 + r == wc * 32 + n * 16 + lr) e = 0.f;
                        rp[m][r] += e;
                    }
        } else {
            #pragma unroll
            for (int m = 0; m < 4; ++m)
                #pragma unroll
                for (int n = 0; n < 2; ++n)
                    #pragma unroll
                    for (int r = 0; r < 4; ++r)
                        rp[m][r] += __builtin_amdgcn_exp2f(acc[m][n][r]);
        }
    }

    // ---- row sums: reduce over lr, store P[row][slot] (32 slots, 128B/row) ----
    #pragma unroll
    for (int m = 0; m < 4; ++m)
        #pragma unroll
        for (int r = 0; r < 4; ++r) {
            float v = rp[m][r];
            v += __shfl_xor(v, 1, 64);
            v += __shfl_xor(v, 2, 64);
            v += __shfl_xor(v, 4, 64);
            v += __shfl_xor(v, 8, 64);
            if (lr == 0) {
                const int row = rb * 128 + wr * 64 + m * 16 + lk * 4 + r;
                if (USEP)
                    ZP[row * 32 + (g * 2 + wc)] = v;
                else
                    atomicAdd(&ZP[row], v);
            }
        }
}

// ------------- final (P path): Z[r] = sum_32 P[r][slot] (contiguous); loss reduce -------------
__global__ void kfinalP(const float* __restrict__ P, const float* __restrict__ pairT,
                        float* __restrict__ out) {
    const int r = blockIdx.x * 256 + threadIdx.x;
    float s = 0.f;
    if (r < B_ROWS - 2) {
        const float4* p4 = reinterpret_cast<const float4*>(P + r * 32);
        float z = 0.f;
        #pragma unroll
        for (int i = 0; i < 8; ++i) {
            const float4 v = p4[i];
            z += v.x + v.y + v.z + v.w;
        }
        s = logf(z);
    }
    if (r < NPAIR) s -= 2.f * pairT[r];
    #pragma unroll
    for (int m = 1; m < 64; m <<= 1) s += __shfl_xor(s, m, 64);
    __shared__ float red[4];
    const int wid = threadIdx.x >> 6;
    const int lane = threadIdx.x & 63;
    if (lane == 0) red[wid] = s;
    __syncthreads();
    if (threadIdx.x == 0) {
        float tsum = red[0] + red[1] + red[2] + red[3];
        atomicAdd(out, tsum / (float)B_ROWS);
    }
}

// ------------- final (Z fallback path) -------------
__global__ void kfinalZ(const float* __restrict__ Z, const float* __restrict__ pairT,
                        float* __restrict__ out) {
    float s = 0.f;
    for (int r = threadIdx.x; r < B_ROWS - 2; r += 1024) s += logf(Z[r]);
    for (int p = threadIdx.x; p < NPAIR; p += 1024) s -= 2.f * pairT[p];
    #pragma unroll
    for (int m = 1; m < 64; m <<= 1) s += __shfl_xor(s, m, 64);
    __shared__ float red[16];
    const int wid = threadIdx.x >> 6;
    const int lane = threadIdx.x & 63;
    if (lane == 0) red[wid] = s;
    __syncthreads();
    if (threadIdx.x == 0) {
        float t = 0.f;
        #pragma unroll
        for (int i = 0; i < 16; ++i) t += red[i];
        out[0] = t / (float)B_ROWS;
    }
}

extern "C" void kernel_launch(void* const* d_in, const int* in_sizes, int n_in,
                              void* d_out, int out_size, void* d_ws, size_t ws_size,
                              hipStream_t stream) {
    (void)in_sizes; (void)n_in; (void)out_size;
    const float* X = (const float*)d_in[0];
    float* out = (float*)d_out;
    char* ws = (char*)d_ws;

    float* Z = (float*)ws;                                   // 32 KB (fallback)
    float* pairT = (float*)(ws + 32768);                     // 16 KB
    __hip_bfloat16* XN = (__hip_bfloat16*)(ws + 49152);      // 2 MB
    float* P = (float*)(ws + 49152 + 2097152);               // 1 MB (8192 x 32 f32)
    const size_t need = 49152 + 2097152 + (size_t)32 * B_ROWS * 4;
    const bool useP = ws_size >= need;

    kprep<<<1024, 256, 0, stream>>>(X, XN, pairT, out);
    if (useP) {
        kgemm<true><<<dim3(16, 64), 256, 0, stream>>>(XN, P);
        kfinalP<<<32, 256, 0, stream>>>(P, pairT, out);
    } else {
        kzero<<<32, 256, 0, stream>>>(Z);
        kgemm<false><<<dim3(16, 64), 256, 0, stream>>>(XN, Z);
        kfinalZ<<<1, 1024, 0, stream>>>(Z, pairT, out);
    }
}

// Round 18
// 34.807 us; speedup vs baseline: 2.3470x; 1.0740x over previous
//
#include <hip/hip_runtime.h>
#include <hip/hip_bf16.h>

typedef __attribute__((ext_vector_type(8))) short short8;
typedef __attribute__((ext_vector_type(4))) float floatx4;

#define B_ROWS 8192
#define DIM 128
#define NPAIR 4095
// rows scaled by sqrt(log2(e)) so S_mfma = S * log2(e) and exp(S) = exp2(S_mfma)
#define RSCALE 1.2011224087864498f

#define GLOAD_LDS16(gp, lp)                                                     \
    __builtin_amdgcn_global_load_lds(                                           \
        (const __attribute__((address_space(1))) void*)(gp),                    \
        (__attribute__((address_space(3))) void*)(lp), 16, 0, 0)

// ---------------- zero Z (fallback path only) ----------------
__global__ void kzero(float* __restrict__ Z) {
    int i = blockIdx.x * 256 + threadIdx.x;
    if (i < B_ROWS) Z[i] = 0.f;
}

// ------------- prep: normalize rows -> bf16 (scaled), exact fp32 pair dots -------------
__global__ void kprep(const float* __restrict__ X, __hip_bfloat16* __restrict__ XN,
                      float* __restrict__ pairT, float* __restrict__ out) {
    const int wid = threadIdx.x >> 6;
    const int lane = threadIdx.x & 63;
    const int j = lane & 31;
    const int W = blockIdx.x * 4 + wid;  // wave index == pair index
    const int row = 2 * W + (lane >> 5);

    const float4 v = *reinterpret_cast<const float4*>(X + row * DIM + j * 4);
    float ss = v.x * v.x + v.y * v.y + v.z * v.z + v.w * v.w;
    #pragma unroll
    for (int m = 1; m < 32; m <<= 1) ss += __shfl_xor(ss, m, 64);  // within half
    const float rn = ss > 0.f ? rsqrtf(ss) : 0.f;

    float4 pv;
    pv.x = __shfl_xor(v.x, 32, 64);
    pv.y = __shfl_xor(v.y, 32, 64);
    pv.z = __shfl_xor(v.z, 32, 64);
    pv.w = __shfl_xor(v.w, 32, 64);
    float pd = v.x * pv.x + v.y * pv.y + v.z * pv.z + v.w * pv.w;
    #pragma unroll
    for (int m = 1; m < 32; m <<= 1) pd += __shfl_xor(pd, m, 64);
    const float rno = __shfl_xor(rn, 32, 64);
    if (lane == 0 && W < NPAIR) pairT[W] = pd * rn * rno;

    const float sc = rn * RSCALE;
    __hip_bfloat162 h0 = __float22bfloat162_rn(make_float2(v.x * sc, v.y * sc));
    __hip_bfloat162 h1 = __float22bfloat162_rn(make_float2(v.z * sc, v.w * sc));
    struct B4 { __hip_bfloat162 a, b; };
    *reinterpret_cast<B4*>(XN + row * DIM + j * 4) = B4{h0, h1};

    if (W == 0 && lane == 0) out[0] = 0.f;
}

// ---- wave-private stage: one 32-col x 128-K bf16 slab (8KB), 8 x 16B per lane ----
// LDS[row][colL] = global[row][colL ^ ((row&7)<<3)] (pre-swizzled source; dest is
// wave-uniform base + lane*16, i.e. naturally wave-private).
__device__ __forceinline__ void stage32w(const __hip_bfloat16* __restrict__ gsrc,
                                         __hip_bfloat16* lbuf, int lane) {
    #pragma unroll
    for (int it = 0; it < 8; ++it) {
        const int e = it * 512 + lane * 8;  // elem offset within slab
        const int src = (e & ~127) | ((e & 127) ^ (((e >> 7) & 7) << 3));
        GLOAD_LDS16(gsrc + src, lbuf + it * 512);
    }
}

// ------------- main: BARRIER-FREE wave-private pipeline GEMM -------------
// grid (8, 64): y = row panel rb (128 rows), x = col group g (1024 cols = 16 slabs
// of 64; wave reads its wc-half = 32 cols, own private copy).
// 4 waves 2x2 (wr row-half, wc col-half), each wave fully self-paced:
//   phase t: vmcnt(8) [own slab t landed; t+1 in flight] -> 8x ds_read ->
//   lgkmcnt(0) -> stage slab t+2 over drained buffer -> 32 MFMA -> 32 exp2.
// Zero s_barrier in the kernel; waves fill each other's stalls.
template <bool USEP>
__global__ void __launch_bounds__(256, 2) kgemm(const __hip_bfloat16* __restrict__ XN,
                                                float* __restrict__ ZP) {
    __shared__ __hip_bfloat16 Bs[4][2][32 * DIM];  // [wave][buf][slab] = 64KB

    const int tid = threadIdx.x;
    const int wid = tid >> 6;
    const int lane = tid & 63;
    const int lr = lane & 15;
    const int lk = lane >> 4;
    const int wr = wid >> 1;
    const int wc = wid & 1;
    const int rb = blockIdx.y;
    const int g = blockIdx.x;

    // A: 64 rows in registers: a[kk][m], rows rb*128 + wr*64 + m*16 + lr
    short8 a[4][4];
    const __hip_bfloat16* Abase = XN + (rb * 128 + wr * 64 + lr) * DIM + lk * 8;
    #pragma unroll
    for (int m = 0; m < 4; ++m)
        #pragma unroll
        for (int kk = 0; kk < 4; ++kk)
            a[kk][m] = *reinterpret_cast<const short8*>(Abase + m * 16 * DIM + kk * 32);

    float rp[4][4];
    #pragma unroll
    for (int m = 0; m < 4; ++m)
        #pragma unroll
        for (int r = 0; r < 4; ++r) rp[m][r] = 0.f;

    const floatx4 zero4 = {0.f, 0.f, 0.f, 0.f};

    // wave's column stream: slab t covers global cols g*1024 + t*64 + wc*32 .. +32
    const __hip_bfloat16* Gcol = XN + (size_t)(g * 1024 + wc * 32) * DIM;
    const int myblk = rb * 2 + wr;  // wave's 64-row block index

    // prologue: stage slabs 0,1 into private buffers
    stage32w(Gcol, &Bs[wid][0][0], lane);
    stage32w(Gcol + (size_t)64 * DIM, &Bs[wid][1][0], lane);

    for (int t = 0; t < 16; ++t) {
        // own-slab wait: 8 loads of slab t retired; slab t+1's 8 stay in flight
        if (t < 15)
            asm volatile("s_waitcnt vmcnt(8)" ::: "memory");
        else
            asm volatile("s_waitcnt vmcnt(0)" ::: "memory");

        const __hip_bfloat16* Bt = &Bs[wid][t & 1][0];

        // B fragments: slab-local cols n*16 + lr (32-row slab), swizzled read
        short8 b[4][2];
        #pragma unroll
        for (int n = 0; n < 2; ++n) {
            const int row = n * 16 + lr;
            #pragma unroll
            for (int kk = 0; kk < 4; ++kk) {
                const int col = (kk * 32 + lk * 8) ^ ((row & 7) << 3);
                b[kk][n] = *reinterpret_cast<const short8*>(&Bt[row * DIM + col]);
            }
        }
        // drain LDS reads so the buffer can be overwritten by slab t+2's DMA
        asm volatile("s_waitcnt lgkmcnt(0)" ::: "memory");
        __builtin_amdgcn_sched_barrier(0);
        if (t + 2 < 16)
            stage32w(Gcol + (size_t)(t + 2) * 64 * DIM, &Bs[wid][t & 1][0], lane);

        __builtin_amdgcn_s_setprio(1);
        floatx4 acc[4][2];
        #pragma unroll
        for (int m = 0; m < 4; ++m)
            #pragma unroll
            for (int n = 0; n < 2; ++n)
                acc[m][n] = __builtin_amdgcn_mfma_f32_16x16x32_bf16(a[0][m], b[0][n], zero4, 0, 0, 0);
        #pragma unroll
        for (int kk = 1; kk < 4; ++kk)
            #pragma unroll
            for (int m = 0; m < 4; ++m)
                #pragma unroll
                for (int n = 0; n < 2; ++n)
                    acc[m][n] = __builtin_amdgcn_mfma_f32_16x16x32_bf16(a[kk][m], b[kk][n], acc[m][n], 0, 0, 0);
        __builtin_amdgcn_s_setprio(0);

        // epilogue: exp2 + row accumulate; diagonal exclusion when this slab's
        // 64-col block equals the wave's 64-row block
        if (g * 16 + t == myblk) {
            #pragma unroll
            for (int m = 0; m < 4; ++m)
                #pragma unroll
                for (int n = 0; n < 2; ++n)
                    #pragma unroll
                    for (int r = 0; r < 4; ++r) {
                        float e = __builtin_amdgcn_exp2f(acc[m][n][r]);
                        if (m * 16 + lk * 4 + r == wc * 32 + n * 16 + lr) e = 0.f;
                        rp[m][r] += e;
                    }
        } else {
            #pragma unroll
            for (int m = 0; m < 4; ++m)
                #pragma unroll
                for (int n = 0; n < 2; ++n)
                    #pragma unroll
                    for (int r = 0; r < 4; ++r)
                        rp[m][r] += __builtin_amdgcn_exp2f(acc[m][n][r]);
        }
    }

    // ---- row sums: reduce over lr, store P[row][slot] (16 slots, 64B/row) ----
    #pragma unroll
    for (int m = 0; m < 4; ++m)
        #pragma unroll
        for (int r = 0; r < 4; ++r) {
            float v = rp[m][r];
            v += __shfl_xor(v, 1, 64);
            v += __shfl_xor(v, 2, 64);
            v += __shfl_xor(v, 4, 64);
            v += __shfl_xor(v, 8, 64);
            if (lr == 0) {
                const int row = rb * 128 + wr * 64 + m * 16 + lk * 4 + r;
                if (USEP)
                    ZP[row * 16 + (g * 2 + wc)] = v;
                else
                    atomicAdd(&ZP[row], v);
            }
        }
}

// ------------- final (P path): Z[r] = sum_16 P[r][slot] (contiguous); loss reduce -------------
__global__ void kfinalP(const float* __restrict__ P, const float* __restrict__ pairT,
                        float* __restrict__ out) {
    const int r = blockIdx.x * 256 + threadIdx.x;
    float s = 0.f;
    if (r < B_ROWS - 2) {
        const float4* p4 = reinterpret_cast<const float4*>(P + r * 16);
        float z = 0.f;
        #pragma unroll
        for (int i = 0; i < 4; ++i) {
            const float4 v = p4[i];
            z += v.x + v.y + v.z + v.w;
        }
        s = logf(z);
    }
    if (r < NPAIR) s -= 2.f * pairT[r];
    #pragma unroll
    for (int m = 1; m < 64; m <<= 1) s += __shfl_xor(s, m, 64);
    __shared__ float red[4];
    const int wid = threadIdx.x >> 6;
    const int lane = threadIdx.x & 63;
    if (lane == 0) red[wid] = s;
    __syncthreads();
    if (threadIdx.x == 0) {
        float tsum = red[0] + red[1] + red[2] + red[3];
        atomicAdd(out, tsum / (float)B_ROWS);
    }
}

// ------------- final (Z fallback path) -------------
__global__ void kfinalZ(const float* __restrict__ Z, const float* __restrict__ pairT,
                        float* __restrict__ out) {
    float s = 0.f;
    for (int r = threadIdx.x; r < B_ROWS - 2; r += 1024) s += logf(Z[r]);
    for (int p = threadIdx.x; p < NPAIR; p += 1024) s -= 2.f * pairT[p];
    #pragma unroll
    for (int m = 1; m < 64; m <<= 1) s += __shfl_xor(s, m, 64);
    __shared__ float red[16];
    const int wid = threadIdx.x >> 6;
    const int lane = threadIdx.x & 63;
    if (lane == 0) red[wid] = s;
    __syncthreads();
    if (threadIdx.x == 0) {
        float t = 0.f;
        #pragma unroll
        for (int i = 0; i < 16; ++i) t += red[i];
        out[0] = t / (float)B_ROWS;
    }
}

extern "C" void kernel_launch(void* const* d_in, const int* in_sizes, int n_in,
                              void* d_out, int out_size, void* d_ws, size_t ws_size,
                              hipStream_t stream) {
    (void)in_sizes; (void)n_in; (void)out_size;
    const float* X = (const float*)d_in[0];
    float* out = (float*)d_out;
    char* ws = (char*)d_ws;

    float* Z = (float*)ws;                                   // 32 KB (fallback)
    float* pairT = (float*)(ws + 32768);                     // 16 KB
    __hip_bfloat16* XN = (__hip_bfloat16*)(ws + 49152);      // 2 MB
    float* P = (float*)(ws + 49152 + 2097152);               // 512 KB (8192 x 16 f32)
    const size_t need = 49152 + 2097152 + (size_t)16 * B_ROWS * 4;
    const bool useP = ws_size >= need;

    kprep<<<1024, 256, 0, stream>>>(X, XN, pairT, out);
    if (useP) {
        kgemm<true><<<dim3(8, 64), 256, 0, stream>>>(XN, P);
        kfinalP<<<32, 256, 0, stream>>>(P, pairT, out);
    } else {
        kzero<<<32, 256, 0, stream>>>(Z);
        kgemm<false><<<dim3(8, 64), 256, 0, stream>>>(XN, Z);
        kfinalZ<<<1, 1024, 0, stream>>>(Z, pairT, out);
    }
}